// Round 20
// baseline (203.544 us; speedup 1.0000x reference)
//
#include <hip/hip_runtime.h>
#include <hip/hip_bf16.h>
#include <math.h>

#define BATCH 4096
#define IDIM 78
#define DM 256
#define DI 1024
#define NL 4

typedef __attribute__((ext_vector_type(8))) short bf16x8;
typedef __attribute__((ext_vector_type(4))) float f32x4;

__device__ __forceinline__ float siluf(float v){ return v / (1.0f + __expf(-v)); }
// branch-free fast softplus: log1p(exp(v)) = max(v,0) + log(1+exp(-|v|))
__device__ __forceinline__ float softplusf(float v){
  return fmaxf(v, 0.f) + __logf(1.f + __expf(-fabsf(v)));
}
__device__ __forceinline__ ushort f2bf(float f){
  union { float f; unsigned u; } c; c.f = f;
  unsigned r = c.u + 0x7fff + ((c.u >> 16) & 1);
  return (ushort)(r >> 16);
}
__device__ __forceinline__ float bf2f(ushort b){
  union { unsigned u; float f; } c; c.u = ((unsigned)b) << 16; return c.f;
}
__device__ __forceinline__ unsigned pack2(float lo, float hi){
  return (unsigned)f2bf(lo) | ((unsigned)f2bf(hi) << 16);
}
// async global->LDS, 16B/lane; LDS dest = wave-uniform base + lane*16; global src per-lane
__device__ __forceinline__ void async_copy16(void* lds, const void* g){
  __builtin_amdgcn_global_load_lds(
      (const __attribute__((address_space(1))) unsigned int*)g,
      (__attribute__((address_space(3))) unsigned int*)lds, 16, 0, 0);
}

// ---------- k_pre: weight prep (WinT*nw fold, WoutT, WxT) + proj_in (h, hb, pssq) ----------
// grid: [0,512) WinT | [512,768) WoutT | [768,848) WxT | [848,1104) proj
__global__ __launch_bounds__(256) void k_pre(const float* __restrict__ Win,
    const float* __restrict__ Wout, const float* __restrict__ Wx,
    const float* __restrict__ nw,
    ushort* __restrict__ WinT, ushort* __restrict__ WoutT, ushort* __restrict__ WxT,
    const float* __restrict__ x, const float* __restrict__ Wp,
    const float* __restrict__ bp,
    float* __restrict__ h, ushort* __restrict__ hb, float* __restrict__ pssq){
  __shared__ __align__(16) char smem[17408];
  int bid = blockIdx.x, t = threadIdx.x;
  if (bid < 768){
    // ---- 64x64 fp32->bf16 transpose tile; Win path folds nw over the k (row) dim ----
    float (*tl)[65] = (float(*)[65])smem;
    const float* src; ushort* dst; int R, C, r0, c0;
    const float* nwl = nullptr;
    if (bid < 512){
      int l = bid>>7, b = bid&127;
      src = Win + (size_t)l*DM*2*DI;  dst = WinT + (size_t)l*2*DI*DM;
      R = DM; C = 2*DI; r0 = (b>>5)*64; c0 = (b&31)*64;
      nwl = nw + l*DM;
    } else {
      int b2 = bid-512; int l = b2>>6, b = b2&63;
      src = Wout + (size_t)l*DI*DM;   dst = WoutT + (size_t)l*DM*DI;
      R = DI; C = DM; r0 = (b>>2)*64; c0 = (b&3)*64;
    }
    int ci4 = (t&15)*4, rq = t>>4;
    #pragma unroll
    for (int p=0;p<4;p++){
      int ri = p*16+rq;
      float4 v = *(const float4*)(src + (size_t)(r0+ri)*C + c0+ci4);
      float s = nwl ? nwl[r0+ri] : 1.0f;
      tl[ri][ci4]=v.x*s; tl[ri][ci4+1]=v.y*s; tl[ri][ci4+2]=v.z*s; tl[ri][ci4+3]=v.w*s;
    }
    __syncthreads();
    // store: 1 pass, 32B/thread (two uint4), 2-way-max LDS bank aliasing
    int orow = t>>2, seg = t&3;
    float e[16];
    #pragma unroll
    for (int q=0;q<16;q++) e[q] = tl[seg*16+q][orow];
    uint4 o0, o1;
    o0.x = pack2(e[ 0],e[ 1]); o0.y = pack2(e[ 2],e[ 3]);
    o0.z = pack2(e[ 4],e[ 5]); o0.w = pack2(e[ 6],e[ 7]);
    o1.x = pack2(e[ 8],e[ 9]); o1.y = pack2(e[10],e[11]);
    o1.z = pack2(e[12],e[13]); o1.w = pack2(e[14],e[15]);
    ushort* dr = dst + (size_t)(c0+orow)*R + r0 + seg*16;
    *(uint4*)dr = o0; *(uint4*)(dr+8) = o1;
  } else if (bid < 848){
    // ---- Wx [l][1024][80] -> WxT [l][80][1024], 4 n-cols/block, float4 reads ----
    float* lw = (float*)smem;            // [4][1040]
    int b = bid-768; int l = b/20, y0 = (b%20)*4;
    const float* src = Wx + (size_t)l*DI*80 + y0;
    #pragma unroll
    for (int p=0;p<4;p++){
      int k = p*256+t;
      float4 v = *(const float4*)(src + (size_t)k*80);
      lw[k] = v.x; lw[1040+k] = v.y; lw[2080+k] = v.z; lw[3120+k] = v.w;
    }
    __syncthreads();
    int yi = t>>6, kk = (t&63)*16;
    const float* s = lw + yi*1040 + kk;
    ushort* dr = WxT + (size_t)l*80*DI + (size_t)(y0+yi)*DI + kk;
    uint4 o0, o1;
    o0.x = pack2(s[ 0],s[ 1]); o0.y = pack2(s[ 2],s[ 3]);
    o0.z = pack2(s[ 4],s[ 5]); o0.w = pack2(s[ 6],s[ 7]);
    o1.x = pack2(s[ 8],s[ 9]); o1.y = pack2(s[10],s[11]);
    o1.z = pack2(s[12],s[13]); o1.w = pack2(s[14],s[15]);
    *(uint4*)dr = o0; *(uint4*)(dr+8) = o1;
  } else {
    // ---- proj_in: h (fp32) + hb (bf16) + pssq[0][row]=ssq (pssq[1..3]=0), 16 rows/block ----
    float (*xs)[80] = (float(*)[80])smem;                 // 5120 B
    float (*sred)[4] = (float(*)[4])(smem + 5120);        // 256 B
    int row0 = (bid - 848)*16;
    int wid = t>>6;
    if (t < IDIM){
      #pragma unroll
      for (int r=0;r<16;r++) xs[r][t] = x[(size_t)(row0+r)*IDIM + t];
    }
    __syncthreads();
    int col = t;
    float acc[16];
    float b0 = bp[col];
    #pragma unroll
    for (int r=0;r<16;r++) acc[r] = b0;
    for (int k=0;k<IDIM;k++){
      float wv = Wp[k*DM + col];
      #pragma unroll
      for (int r=0;r<16;r++) acc[r] = fmaf(xs[r][k], wv, acc[r]);
    }
    #pragma unroll
    for (int r=0;r<16;r++){
      float sq = acc[r]*acc[r];
      #pragma unroll
      for (int o=32;o>0;o>>=1) sq += __shfl_xor(sq, o);
      if ((t&63)==0) sred[r][wid] = sq;
    }
    #pragma unroll
    for (int r=0;r<16;r++){
      size_t o = (size_t)(row0+r)*DM + col;
      h[o] = acc[r];
      hb[o] = f2bf(acc[r]);
    }
    __syncthreads();
    if (t < 16){
      int row = row0 + t;
      pssq[row] = sred[t][0]+sred[t][1]+sred[t][2]+sred[t][3];
      pssq[BATCH+row] = 0.f; pssq[2*BATCH+row] = 0.f; pssq[3*BATCH+row] = 0.f;
    }
  }
}

// ---------- k_blk0: 64x128 tile, 4 waves (2x2), 2x4 frags/wave, BK=32 dbuf 2-phase ----------
// (hb @ WinT'^T) * sc[row] ; conv/silu epilogue via LDS-staged coalesced stores
__global__ __launch_bounds__(256, 4) void k_blk0(
    const ushort* __restrict__ A,     // hb [4096][256]
    const float* __restrict__ pq,     // pssq [4][4096]
    const ushort* __restrict__ Bt,    // WinT' [2048][256] (nw folded)
    const float* __restrict__ cwl, const float* __restrict__ cbl,
    ushort* __restrict__ xi, ushort* __restrict__ sz)
{
  // LDS: A dbuf 2x2048 ushorts (4 KB x2), B dbuf 2x4096 (8 KB x2) = 24 KB total
  __shared__ __align__(16) ushort lds[12288];
  __shared__ float ssc_l[64];
  int t = threadIdx.x, w = t>>6, lane = t&63;
  int wr = w>>1, wc = w&1;
  int lr = lane&15, lk = lane>>4;
  int row0 = blockIdx.x*64, col0 = blockIdx.y*128;
  // staging: per inst, lane covers (row = lane>>2, chunk = lane&3); src chunk pre-swizzled
  int srow = lane>>2;
  int ssw = (lane&3) ^ ((lane>>3)&3);    // (chunk ^ ((ldsrow>>1)&3))
  const ushort* Ag = A  + (size_t)(row0 + srow)*DM + ssw*8;
  const ushort* Bg = Bt + (size_t)(col0 + srow)*DM + ssw*8;
  int rsw = (lk ^ ((lr>>1)&3))*8;        // read-side same involution

  if (t < 64){
    int row = row0 + t;
    float s = pq[row] + pq[BATCH+row] + pq[2*BATCH+row] + pq[3*BATCH+row];
    ssc_l[t] = rsqrtf(s*(1.0f/DM) + 1e-5f);
  }

  #define AS(buf) (lds + (buf)*2048)
  #define BS(buf) (lds + 4096 + (buf)*4096)
  // stage one K-step tile: 12 insts split 3/wave (1 A: rows w*16..+16; 2 B: rows w*32..+32)
  #define STAGE(buf, tt) { \
    int ko = (tt)*32; \
    async_copy16(AS(buf) + w*16*32, Ag + (size_t)w*16*DM + ko); \
    async_copy16(BS(buf) + (w*32)*32, Bg + (size_t)(w*32)*DM + ko); \
    async_copy16(BS(buf) + (w*32+16)*32, Bg + (size_t)(w*32+16)*DM + ko); }

  f32x4 acc[2][4] = {};
  STAGE(0, 0);
  __syncthreads();
  int cur = 0;
  #pragma unroll
  for (int tt=0; tt<8; ++tt){
    if (tt < 7) STAGE(cur^1, tt+1);
    bf16x8 av[2], bv[4];
    #pragma unroll
    for (int i=0;i<2;i++) av[i] = *(const bf16x8*)(AS(cur) + (wr*32 + i*16 + lr)*32 + rsw);
    #pragma unroll
    for (int j=0;j<4;j++) bv[j] = *(const bf16x8*)(BS(cur) + (wc*64 + j*16 + lr)*32 + rsw);
    #pragma unroll
    for (int i=0;i<2;i++)
      #pragma unroll
      for (int j=0;j<4;j++)
        acc[i][j] = __builtin_amdgcn_mfma_f32_16x16x32_bf16(av[i], bv[j], acc[i][j], 0,0,0);
    __syncthreads();
    cur ^= 1;
  }

  // epilogue: *sc[row] -> conv/silu -> bf16 tile in LDS -> coalesced uint4 stores
  const bool is_xi = (col0 < DI);
  float scw[4], scb[4];
  if (is_xi){
    #pragma unroll
    for (int j=0;j<4;j++){
      int colb = col0 + wc*64 + j*16 + lr;
      scw[j] = cwl[colb*16+15];
      scb[j] = cbl[colb];
    }
  }
  ushort* cs = lds;                      // [64][136] = 8704 ushorts <= 12288
  #pragma unroll
  for (int i=0;i<2;i++)
    #pragma unroll
    for (int j=0;j<4;j++){
      int cl = wc*64 + j*16 + lr;
      #pragma unroll
      for (int r=0;r<4;r++){
        int rl = wr*32 + i*16 + lk*4 + r;
        float v = acc[i][j][r] * ssc_l[rl];
        cs[rl*136 + cl] = f2bf(is_xi ? siluf(fmaf(scw[j], v, scb[j])) : siluf(v));
      }
    }
  __syncthreads();
  int rl = t>>2, q = t&3;
  ushort* drow = (is_xi ? (xi + col0) : (sz + col0 - DI)) + (size_t)(row0+rl)*DI + q*32;
  const ushort* srcr = cs + rl*136 + q*32;
  #pragma unroll
  for (int u=0;u<4;u++)
    *(uint4*)&drow[u*8] = *(const uint4*)&srcr[u*8];
  #undef AS
  #undef BS
  #undef STAGE
}

// ---------- k_ssm: 8 rows/block (512 blocks = 2 blocks/CU), fused dbc + delta + gating ----------
// dsum stride 84 (2-way bank aliasing); phase-1 pads A-rows via lr&7; phase-2 depth-2 prefetch.
__global__ __launch_bounds__(512) void k_ssm(const ushort* __restrict__ xi, const ushort* __restrict__ sz,
    const ushort* __restrict__ WxT, const float* __restrict__ Wdt, const float* __restrict__ bdt,
    const float* __restrict__ Dd, ushort* __restrict__ y){
  __shared__ float dsum[8][8][84];
  __shared__ __align__(16) float dbcc[8][16];    // compact dbc[:, :16] for phase 2
  __shared__ float sS[8];
  int r0 = blockIdx.x*8;
  int t = threadIdx.x, w = t>>6, lane = t&63, lr = lane&15, lk = lane>>4;
  f32x4 acc[5] = {};
  const ushort* Ab = xi  + (size_t)(r0+(lr&7))*DI + w*128 + lk*8;  // rows padded: frag rows 8..15 duplicate 0..7
  const ushort* Bb = WxT + (size_t)lr*DI      + w*128 + lk*8;
  #pragma unroll
  for (int s=0;s<4;s++){
    bf16x8 a = *(const bf16x8*)(Ab + s*32);
    #pragma unroll
    for (int j=0;j<5;j++){
      bf16x8 b = *(const bf16x8*)(Bb + (size_t)j*16*DI + s*32);
      acc[j] = __builtin_amdgcn_mfma_f32_16x16x32_bf16(a, b, acc[j], 0,0,0);
    }
  }
  if (lk < 2){                                    // only m=0..7 rows are real
    #pragma unroll
    for (int j=0;j<5;j++)
      #pragma unroll
      for (int r=0;r<4;r++)
        dsum[w][lk*4+r][j*16+lr] = acc[j][r];
  }
  __syncthreads();
  for (int idx=t; idx<8*80; idx+=512){
    int rr = idx/80, n = idx%80;
    float s = dsum[0][rr][n];
    #pragma unroll
    for (int q=1;q<8;q++) s += dsum[q][rr][n];
    dsum[0][rr][n] = s;
    if (n < 16) dbcc[rr][n] = s;
  }
  __syncthreads();
  if (t < 128){
    int row = t>>4, ln = t&15;
    float p = dsum[0][row][16+ln]*dsum[0][row][48+ln]
            + dsum[0][row][32+ln]*dsum[0][row][64+ln];
    p += __shfl_xor(p, 8); p += __shfl_xor(p, 4); p += __shfl_xor(p, 2); p += __shfl_xor(p, 1);
    if (ln==0) sS[row] = p;
  }
  __syncthreads();
  int e = 2*t;
  float2 wdtr[16];
  #pragma unroll
  for (int r=0;r<16;r++) wdtr[r] = *(const float2*)(Wdt + (size_t)r*DI + e);
  float2 bd = *(const float2*)(bdt + e);
  float2 dd = *(const float2*)(Dd + e);
  // depth-2 rotating prefetch of xi/sz
  unsigned xp0 = *(const unsigned*)(xi + (size_t)(r0+0)*DI + e);
  unsigned zp0 = *(const unsigned*)(sz + (size_t)(r0+0)*DI + e);
  unsigned xp1 = *(const unsigned*)(xi + (size_t)(r0+1)*DI + e);
  unsigned zp1 = *(const unsigned*)(sz + (size_t)(r0+1)*DI + e);
  #pragma unroll
  for (int row=0; row<8; ++row){
    unsigned cx = xp0, cz = zp0;
    xp0 = xp1; zp0 = zp1;
    if (row < 6){
      xp1 = *(const unsigned*)(xi + (size_t)(r0+row+2)*DI + e);
      zp1 = *(const unsigned*)(sz + (size_t)(r0+row+2)*DI + e);
    }
    float4 d0 = *(const float4*)&dbcc[row][0];
    float4 d1 = *(const float4*)&dbcc[row][4];
    float4 d2 = *(const float4*)&dbcc[row][8];
    float4 d3 = *(const float4*)&dbcc[row][12];
    float u0 = bd.x, u1 = bd.y;
    u0 = fmaf(wdtr[ 0].x, d0.x, u0); u1 = fmaf(wdtr[ 0].y, d0.x, u1);
    u0 = fmaf(wdtr[ 1].x, d0.y, u0); u1 = fmaf(wdtr[ 1].y, d0.y, u1);
    u0 = fmaf(wdtr[ 2].x, d0.z, u0); u1 = fmaf(wdtr[ 2].y, d0.z, u1);
    u0 = fmaf(wdtr[ 3].x, d0.w, u0); u1 = fmaf(wdtr[ 3].y, d0.w, u1);
    u0 = fmaf(wdtr[ 4].x, d1.x, u0); u1 = fmaf(wdtr[ 4].y, d1.x, u1);
    u0 = fmaf(wdtr[ 5].x, d1.y, u0); u1 = fmaf(wdtr[ 5].y, d1.y, u1);
    u0 = fmaf(wdtr[ 6].x, d1.z, u0); u1 = fmaf(wdtr[ 6].y, d1.z, u1);
    u0 = fmaf(wdtr[ 7].x, d1.w, u0); u1 = fmaf(wdtr[ 7].y, d1.w, u1);
    u0 = fmaf(wdtr[ 8].x, d2.x, u0); u1 = fmaf(wdtr[ 8].y, d2.x, u1);
    u0 = fmaf(wdtr[ 9].x, d2.y, u0); u1 = fmaf(wdtr[ 9].y, d2.y, u1);
    u0 = fmaf(wdtr[10].x, d2.z, u0); u1 = fmaf(wdtr[10].y, d2.z, u1);
    u0 = fmaf(wdtr[11].x, d2.w, u0); u1 = fmaf(wdtr[11].y, d2.w, u1);
    u0 = fmaf(wdtr[12].x, d3.x, u0); u1 = fmaf(wdtr[12].y, d3.x, u1);
    u0 = fmaf(wdtr[13].x, d3.y, u0); u1 = fmaf(wdtr[13].y, d3.y, u1);
    u0 = fmaf(wdtr[14].x, d3.z, u0); u1 = fmaf(wdtr[14].y, d3.z, u1);
    u0 = fmaf(wdtr[15].x, d3.w, u0); u1 = fmaf(wdtr[15].y, d3.w, u1);
    float srow = sS[row];
    float dl0 = softplusf(u0), dl1 = softplusf(u1);
    ushort2 xvv = *(ushort2*)&cx;
    ushort2 zvv = *(ushort2*)&cz;
    ushort2 ov;
    ov.x = f2bf(bf2f(xvv.x) * fmaf(dl0, srow, dd.x) * bf2f(zvv.x));
    ov.y = f2bf(bf2f(xvv.y) * fmaf(dl1, srow, dd.y) * bf2f(zvv.y));
    size_t o = (size_t)(r0+row)*DI + e;
    *(ushort2*)(y + o) = ov;
  }
}

// ---------- k_blk1: 32x64 tile, BK=256 one-shot chunks, y @ WoutT^T -> h +=, hb, pssq (+pfin last) ----------
__global__ __launch_bounds__(256) void k_blk1(
    const ushort* __restrict__ A,    // y [4096][1024]
    const ushort* __restrict__ Bt,   // WoutT [256][1024]
    float* __restrict__ h, ushort* __restrict__ hb, float* __restrict__ pssq,
    const float* __restrict__ Wf, float* __restrict__ pfin)
{
  __shared__ __align__(16) ushort As[32][256];  // 16 KB
  __shared__ __align__(16) ushort Bs[64][256];  // 32 KB
  int t = threadIdx.x, wid = t>>6, lane = t&63;
  int wr = wid>>1, wc = wid&1, lr = lane&15, lk = lane>>4;
  int row0 = blockIdx.x*32, col0 = blockIdx.y*64;
  int lrow = lane>>5, lch = lane&31;
  f32x4 acc[2] = {};

  for (int kc=0; kc<4; ++kc){
    int ko = kc*256;
    #pragma unroll
    for (int q=0;q<4;q++){
      int rr = wid*8 + q*2 + lrow;
      async_copy16(&As[wid*8 + q*2][0], A  + (size_t)(row0+rr)*DI + ko + ((lch ^ (rr&7))<<3));
    }
    #pragma unroll
    for (int q=0;q<8;q++){
      int rr = wid*16 + q*2 + lrow;
      async_copy16(&Bs[wid*16 + q*2][0], Bt + (size_t)(col0+rr)*DI + ko + ((lch ^ (rr&7))<<3));
    }
    __syncthreads();
    #pragma unroll
    for (int kk=0;kk<8;kk++){
      int rr = wr*16 + lr;
      bf16x8 a = *(const bf16x8*)&As[rr][(((kk<<2)|lk) ^ (rr&7))<<3];
      #pragma unroll
      for (int j=0;j<2;j++){
        int cc = wc*32 + j*16 + lr;
        bf16x8 b = *(const bf16x8*)&Bs[cc][(((kk<<2)|lk) ^ (cc&7))<<3];
        acc[j] = __builtin_amdgcn_mfma_f32_16x16x32_bf16(a, b, acc[j], 0,0,0);
      }
    }
    __syncthreads();
  }

  float* ls = (float*)&As[0][0];          // [32][68]
  #pragma unroll
  for (int j=0;j<2;j++){
    int cl = wc*32 + j*16 + lr;
    #pragma unroll
    for (int r=0;r<4;r++)
      ls[(wr*16 + lk*4 + r)*68 + cl] = acc[j][r];
  }
  __syncthreads();
  int rl = t>>3, c8 = (t&7)*8;
  size_t o = (size_t)(row0+rl)*DM + col0 + c8;
  float4 hv0, hv1;
  {
    float4 add = *(float4*)&ls[rl*68 + c8];
    hv0 = *(float4*)&h[o];
    hv0.x += add.x; hv0.y += add.y; hv0.z += add.z; hv0.w += add.w;
    *(float4*)&h[o] = hv0;
  }
  {
    float4 add = *(float4*)&ls[rl*68 + c8 + 4];
    hv1 = *(float4*)&h[o + 4];
    hv1.x += add.x; hv1.y += add.y; hv1.z += add.z; hv1.w += add.w;
    *(float4*)&h[o + 4] = hv1;
  }
  // bf16 copy for next layer's A-operand
  uint4 hw;
  hw.x = pack2(hv0.x, hv0.y); hw.y = pack2(hv0.z, hv0.w);
  hw.z = pack2(hv1.x, hv1.y); hw.w = pack2(hv1.z, hv1.w);
  *(uint4*)(hb + o) = hw;
  // per-colblock ssq partial
  float sq = hv0.x*hv0.x + hv0.y*hv0.y + hv0.z*hv0.z + hv0.w*hv0.w
           + hv1.x*hv1.x + hv1.y*hv1.y + hv1.z*hv1.z + hv1.w*hv1.w;
  sq += __shfl_xor(sq, 1); sq += __shfl_xor(sq, 2); sq += __shfl_xor(sq, 4);
  if ((t&7)==0) pssq[(size_t)blockIdx.y*BATCH + row0 + rl] = sq;
  // last layer: per-colblock final-dot partial
  if (Wf){
    const float* wfp = Wf + col0 + c8;
    float pf = hv0.x*wfp[0] + hv0.y*wfp[1] + hv0.z*wfp[2] + hv0.w*wfp[3]
             + hv1.x*wfp[4] + hv1.y*wfp[5] + hv1.z*wfp[6] + hv1.w*wfp[7];
    pf += __shfl_xor(pf, 1); pf += __shfl_xor(pf, 2); pf += __shfl_xor(pf, 4);
    if ((t&7)==0) pfin[(size_t)blockIdx.y*BATCH + row0 + rl] = pf;
  }
}

// ---------- k_final: out = sigmoid(sum pfin + bf) ----------
__global__ __launch_bounds__(256) void k_final(const float* __restrict__ pfin,
    const float* __restrict__ bf, float* __restrict__ out){
  int i = blockIdx.x*256 + threadIdx.x;
  float ft = pfin[i] + pfin[BATCH+i] + pfin[2*BATCH+i] + pfin[3*BATCH+i] + bf[0];
  out[i] = 1.0f/(1.0f + __expf(-ft));
}

extern "C" void kernel_launch(void* const* d_in, const int* in_sizes, int n_in,
                              void* d_out, int out_size, void* d_ws, size_t ws_size,
                              hipStream_t stream){
  const float* x   = (const float*)d_in[0];
  const float* Wp  = (const float*)d_in[1];
  const float* bp  = (const float*)d_in[2];
  const float* nw  = (const float*)d_in[3];
  const float* Win = (const float*)d_in[4];
  const float* cw  = (const float*)d_in[5];
  const float* cb  = (const float*)d_in[6];
  const float* Wx  = (const float*)d_in[7];
  const float* Wdt = (const float*)d_in[8];
  const float* bdt = (const float*)d_in[9];
  const float* Dd  = (const float*)d_in[11];   // A_log (d_in[10]) is dead: scan length 1, h0 = 0
  const float* Wout= (const float*)d_in[12];
  const float* Wf  = (const float*)d_in[13];
  const float* bf  = (const float*)d_in[14];
  float* out = (float*)d_out;

  char* wsb = (char*)d_ws;
  float*  h    = (float*)wsb;  wsb += (size_t)BATCH*DM*4;          // 4 MB
  ushort* hb   = (ushort*)wsb; wsb += (size_t)BATCH*DM*2;          // 2 MB
  ushort* xi   = (ushort*)wsb; wsb += (size_t)BATCH*DI*2;          // 8 MB
  ushort* sz   = (ushort*)wsb; wsb += (size_t)BATCH*DI*2;          // 8 MB
  ushort* WinT = (ushort*)wsb; wsb += (size_t)NL*2*DI*DM*2;        // 4 MB
  ushort* WoutT= (ushort*)wsb; wsb += (size_t)NL*DM*DI*2;          // 2 MB
  ushort* WxT  = (ushort*)wsb; wsb += (size_t)NL*80*DI*2;          // 0.64 MB
  float*  pssq = (float*)wsb;  wsb += (size_t)4*BATCH*4;           // 64 KB
  float*  pfin = (float*)wsb;  wsb += (size_t)4*BATCH*4;           // 64 KB

  k_pre<<<1104, 256, 0, stream>>>(Win, Wout, Wx, nw, WinT, WoutT, WxT,
                                  x, Wp, bp, h, hb, pssq);
  for (int l=0;l<NL;l++){
    k_blk0<<<dim3(BATCH/64, (2*DI)/128), 256, 0, stream>>>(
        hb, pssq, WinT + (size_t)l*2*DI*DM,
        cw + (size_t)l*DI*16, cb + (size_t)l*DI, xi, sz);
    k_ssm<<<BATCH/8, 512, 0, stream>>>(xi, sz, WxT + (size_t)l*80*DI,
        Wdt + (size_t)l*16*DI, bdt + (size_t)l*DI, Dd + (size_t)l*DI, xi);
    k_blk1<<<dim3(BATCH/32, DM/64), 256, 0, stream>>>(
        xi, WoutT + (size_t)l*DM*DI, h, hb, pssq,
        (l == NL-1) ? Wf : nullptr, pfin);
  }
  k_final<<<BATCH/256, 256, 0, stream>>>(pfin, bf, out);
}

// Round 21
// 186.768 us; speedup vs baseline: 1.0898x; 1.0898x over previous
//
#include <hip/hip_runtime.h>
#include <hip/hip_bf16.h>
#include <math.h>

#define BATCH 4096
#define IDIM 78
#define DM 256
#define DI 1024
#define NL 4

typedef __attribute__((ext_vector_type(8))) short bf16x8;
typedef __attribute__((ext_vector_type(4))) float f32x4;

__device__ __forceinline__ float siluf(float v){ return v / (1.0f + __expf(-v)); }
// branch-free fast softplus: log1p(exp(v)) = max(v,0) + log(1+exp(-|v|))
__device__ __forceinline__ float softplusf(float v){
  return fmaxf(v, 0.f) + __logf(1.f + __expf(-fabsf(v)));
}
__device__ __forceinline__ ushort f2bf(float f){
  union { float f; unsigned u; } c; c.f = f;
  unsigned r = c.u + 0x7fff + ((c.u >> 16) & 1);
  return (ushort)(r >> 16);
}
__device__ __forceinline__ float bf2f(ushort b){
  union { unsigned u; float f; } c; c.u = ((unsigned)b) << 16; return c.f;
}
__device__ __forceinline__ unsigned pack2(float lo, float hi){
  return (unsigned)f2bf(lo) | ((unsigned)f2bf(hi) << 16);
}
// async global->LDS, 16B/lane; LDS dest = wave-uniform base + lane*16; global src per-lane
__device__ __forceinline__ void async_copy16(void* lds, const void* g){
  __builtin_amdgcn_global_load_lds(
      (const __attribute__((address_space(1))) unsigned int*)g,
      (__attribute__((address_space(3))) unsigned int*)lds, 16, 0, 0);
}

// ---------- k_pre: weight prep (WinT*nw fold, WoutT, WxT) + proj_in (h, hb, pssq) ----------
// grid: [0,512) WinT | [512,768) WoutT | [768,848) WxT | [848,1104) proj
__global__ __launch_bounds__(256) void k_pre(const float* __restrict__ Win,
    const float* __restrict__ Wout, const float* __restrict__ Wx,
    const float* __restrict__ nw,
    ushort* __restrict__ WinT, ushort* __restrict__ WoutT, ushort* __restrict__ WxT,
    const float* __restrict__ x, const float* __restrict__ Wp,
    const float* __restrict__ bp,
    float* __restrict__ h, ushort* __restrict__ hb, float* __restrict__ pssq){
  __shared__ __align__(16) char smem[17408];
  int bid = blockIdx.x, t = threadIdx.x;
  if (bid < 768){
    // ---- 64x64 fp32->bf16 transpose tile; Win path folds nw over the k (row) dim ----
    float (*tl)[65] = (float(*)[65])smem;
    const float* src; ushort* dst; int R, C, r0, c0;
    const float* nwl = nullptr;
    if (bid < 512){
      int l = bid>>7, b = bid&127;
      src = Win + (size_t)l*DM*2*DI;  dst = WinT + (size_t)l*2*DI*DM;
      R = DM; C = 2*DI; r0 = (b>>5)*64; c0 = (b&31)*64;
      nwl = nw + l*DM;
    } else {
      int b2 = bid-512; int l = b2>>6, b = b2&63;
      src = Wout + (size_t)l*DI*DM;   dst = WoutT + (size_t)l*DM*DI;
      R = DI; C = DM; r0 = (b>>2)*64; c0 = (b&3)*64;
    }
    int ci4 = (t&15)*4, rq = t>>4;
    #pragma unroll
    for (int p=0;p<4;p++){
      int ri = p*16+rq;
      float4 v = *(const float4*)(src + (size_t)(r0+ri)*C + c0+ci4);
      float s = nwl ? nwl[r0+ri] : 1.0f;
      tl[ri][ci4]=v.x*s; tl[ri][ci4+1]=v.y*s; tl[ri][ci4+2]=v.z*s; tl[ri][ci4+3]=v.w*s;
    }
    __syncthreads();
    // store: 1 pass, 32B/thread (two uint4), 2-way-max LDS bank aliasing
    int orow = t>>2, seg = t&3;
    float e[16];
    #pragma unroll
    for (int q=0;q<16;q++) e[q] = tl[seg*16+q][orow];
    uint4 o0, o1;
    o0.x = pack2(e[ 0],e[ 1]); o0.y = pack2(e[ 2],e[ 3]);
    o0.z = pack2(e[ 4],e[ 5]); o0.w = pack2(e[ 6],e[ 7]);
    o1.x = pack2(e[ 8],e[ 9]); o1.y = pack2(e[10],e[11]);
    o1.z = pack2(e[12],e[13]); o1.w = pack2(e[14],e[15]);
    ushort* dr = dst + (size_t)(c0+orow)*R + r0 + seg*16;
    *(uint4*)dr = o0; *(uint4*)(dr+8) = o1;
  } else if (bid < 848){
    // ---- Wx [l][1024][80] -> WxT [l][80][1024], 4 n-cols/block, float4 reads ----
    float* lw = (float*)smem;            // [4][1040]
    int b = bid-768; int l = b/20, y0 = (b%20)*4;
    const float* src = Wx + (size_t)l*DI*80 + y0;
    #pragma unroll
    for (int p=0;p<4;p++){
      int k = p*256+t;
      float4 v = *(const float4*)(src + (size_t)k*80);
      lw[k] = v.x; lw[1040+k] = v.y; lw[2080+k] = v.z; lw[3120+k] = v.w;
    }
    __syncthreads();
    int yi = t>>6, kk = (t&63)*16;
    const float* s = lw + yi*1040 + kk;
    ushort* dr = WxT + (size_t)l*80*DI + (size_t)(y0+yi)*DI + kk;
    uint4 o0, o1;
    o0.x = pack2(s[ 0],s[ 1]); o0.y = pack2(s[ 2],s[ 3]);
    o0.z = pack2(s[ 4],s[ 5]); o0.w = pack2(s[ 6],s[ 7]);
    o1.x = pack2(s[ 8],s[ 9]); o1.y = pack2(s[10],s[11]);
    o1.z = pack2(s[12],s[13]); o1.w = pack2(s[14],s[15]);
    *(uint4*)dr = o0; *(uint4*)(dr+8) = o1;
  } else {
    // ---- proj_in: h (fp32) + hb (bf16) + pssq[0][row]=ssq (pssq[1..3]=0), 16 rows/block ----
    float (*xs)[80] = (float(*)[80])smem;                 // 5120 B
    float (*sred)[4] = (float(*)[4])(smem + 5120);        // 256 B
    int row0 = (bid - 848)*16;
    int wid = t>>6;
    if (t < IDIM){
      #pragma unroll
      for (int r=0;r<16;r++) xs[r][t] = x[(size_t)(row0+r)*IDIM + t];
    }
    __syncthreads();
    int col = t;
    float acc[16];
    float b0 = bp[col];
    #pragma unroll
    for (int r=0;r<16;r++) acc[r] = b0;
    for (int k=0;k<IDIM;k++){
      float wv = Wp[k*DM + col];
      #pragma unroll
      for (int r=0;r<16;r++) acc[r] = fmaf(xs[r][k], wv, acc[r]);
    }
    #pragma unroll
    for (int r=0;r<16;r++){
      float sq = acc[r]*acc[r];
      #pragma unroll
      for (int o=32;o>0;o>>=1) sq += __shfl_xor(sq, o);
      if ((t&63)==0) sred[r][wid] = sq;
    }
    #pragma unroll
    for (int r=0;r<16;r++){
      size_t o = (size_t)(row0+r)*DM + col;
      h[o] = acc[r];
      hb[o] = f2bf(acc[r]);
    }
    __syncthreads();
    if (t < 16){
      int row = row0 + t;
      pssq[row] = sred[t][0]+sred[t][1]+sred[t][2]+sred[t][3];
      pssq[BATCH+row] = 0.f; pssq[2*BATCH+row] = 0.f; pssq[3*BATCH+row] = 0.f;
    }
  }
}

// ---------- k_blk0: 64x128 tile, 4 waves (2x2), 2x4 frags/wave, BK=32 dbuf 2-phase ----------
// (hb @ WinT'^T) * sc[row] ; conv/silu epilogue via LDS-staged coalesced stores
__global__ __launch_bounds__(256, 4) void k_blk0(
    const ushort* __restrict__ A,     // hb [4096][256]
    const float* __restrict__ pq,     // pssq [4][4096]
    const ushort* __restrict__ Bt,    // WinT' [2048][256] (nw folded)
    const float* __restrict__ cwl, const float* __restrict__ cbl,
    ushort* __restrict__ xi, ushort* __restrict__ sz)
{
  // LDS: A dbuf 2x2048 ushorts (4 KB x2), B dbuf 2x4096 (8 KB x2) = 24 KB total
  __shared__ __align__(16) ushort lds[12288];
  __shared__ float ssc_l[64];
  int t = threadIdx.x, w = t>>6, lane = t&63;
  int wr = w>>1, wc = w&1;
  int lr = lane&15, lk = lane>>4;
  int row0 = blockIdx.x*64, col0 = blockIdx.y*128;
  // staging: per inst, lane covers (row = lane>>2, chunk = lane&3); src chunk pre-swizzled
  int srow = lane>>2;
  int ssw = (lane&3) ^ ((lane>>3)&3);    // (chunk ^ ((ldsrow>>1)&3))
  const ushort* Ag = A  + (size_t)(row0 + srow)*DM + ssw*8;
  const ushort* Bg = Bt + (size_t)(col0 + srow)*DM + ssw*8;
  int rsw = (lk ^ ((lr>>1)&3))*8;        // read-side same involution

  if (t < 64){
    int row = row0 + t;
    float s = pq[row] + pq[BATCH+row] + pq[2*BATCH+row] + pq[3*BATCH+row];
    ssc_l[t] = rsqrtf(s*(1.0f/DM) + 1e-5f);
  }

  #define AS(buf) (lds + (buf)*2048)
  #define BS(buf) (lds + 4096 + (buf)*4096)
  // stage one K-step tile: 12 insts split 3/wave (1 A: rows w*16..+16; 2 B: rows w*32..+32)
  #define STAGE(buf, tt) { \
    int ko = (tt)*32; \
    async_copy16(AS(buf) + w*16*32, Ag + (size_t)w*16*DM + ko); \
    async_copy16(BS(buf) + (w*32)*32, Bg + (size_t)(w*32)*DM + ko); \
    async_copy16(BS(buf) + (w*32+16)*32, Bg + (size_t)(w*32+16)*DM + ko); }

  f32x4 acc[2][4] = {};
  STAGE(0, 0);
  __syncthreads();
  int cur = 0;
  #pragma unroll
  for (int tt=0; tt<8; ++tt){
    if (tt < 7) STAGE(cur^1, tt+1);
    bf16x8 av[2], bv[4];
    #pragma unroll
    for (int i=0;i<2;i++) av[i] = *(const bf16x8*)(AS(cur) + (wr*32 + i*16 + lr)*32 + rsw);
    #pragma unroll
    for (int j=0;j<4;j++) bv[j] = *(const bf16x8*)(BS(cur) + (wc*64 + j*16 + lr)*32 + rsw);
    #pragma unroll
    for (int i=0;i<2;i++)
      #pragma unroll
      for (int j=0;j<4;j++)
        acc[i][j] = __builtin_amdgcn_mfma_f32_16x16x32_bf16(av[i], bv[j], acc[i][j], 0,0,0);
    __syncthreads();
    cur ^= 1;
  }

  // epilogue: *sc[row] -> conv/silu -> bf16 tile in LDS -> coalesced uint4 stores
  const bool is_xi = (col0 < DI);
  float scw[4], scb[4];
  if (is_xi){
    #pragma unroll
    for (int j=0;j<4;j++){
      int colb = col0 + wc*64 + j*16 + lr;
      scw[j] = cwl[colb*16+15];
      scb[j] = cbl[colb];
    }
  }
  ushort* cs = lds;                      // [64][136] = 8704 ushorts <= 12288
  #pragma unroll
  for (int i=0;i<2;i++)
    #pragma unroll
    for (int j=0;j<4;j++){
      int cl = wc*64 + j*16 + lr;
      #pragma unroll
      for (int r=0;r<4;r++){
        int rl = wr*32 + i*16 + lk*4 + r;
        float v = acc[i][j][r] * ssc_l[rl];
        cs[rl*136 + cl] = f2bf(is_xi ? siluf(fmaf(scw[j], v, scb[j])) : siluf(v));
      }
    }
  __syncthreads();
  int rl = t>>2, q = t&3;
  ushort* drow = (is_xi ? (xi + col0) : (sz + col0 - DI)) + (size_t)(row0+rl)*DI + q*32;
  const ushort* srcr = cs + rl*136 + q*32;
  #pragma unroll
  for (int u=0;u<4;u++)
    *(uint4*)&drow[u*8] = *(const uint4*)&srcr[u*8];
  #undef AS
  #undef BS
  #undef STAGE
}

// ---------- k_ssm: fused dbc (MFMA split-K) + delta + gating; in-place y over xi ----------
// dsum stride 84 (2-way bank aliasing on phase-1 stores); phase-2 depth-2 xi/sz prefetch.
__global__ __launch_bounds__(512) void k_ssm(const ushort* __restrict__ xi, const ushort* __restrict__ sz,
    const ushort* __restrict__ WxT, const float* __restrict__ Wdt, const float* __restrict__ bdt,
    const float* __restrict__ Dd, ushort* __restrict__ y){
  __shared__ float dsum[8][16][84];
  __shared__ __align__(16) float dbcc[16][16];   // compact dbc[:, :16] for phase 2
  __shared__ float sS[16];
  int r0 = blockIdx.x*16;
  int t = threadIdx.x, w = t>>6, lane = t&63, lr = lane&15, lk = lane>>4;
  f32x4 acc[5] = {};
  const ushort* Ab = xi  + (size_t)(r0+lr)*DI + w*128 + lk*8;
  const ushort* Bb = WxT + (size_t)lr*DI      + w*128 + lk*8;
  #pragma unroll
  for (int s=0;s<4;s++){
    bf16x8 a = *(const bf16x8*)(Ab + s*32);
    #pragma unroll
    for (int j=0;j<5;j++){
      bf16x8 b = *(const bf16x8*)(Bb + (size_t)j*16*DI + s*32);
      acc[j] = __builtin_amdgcn_mfma_f32_16x16x32_bf16(a, b, acc[j], 0,0,0);
    }
  }
  #pragma unroll
  for (int j=0;j<5;j++)
    #pragma unroll
    for (int r=0;r<4;r++)
      dsum[w][lk*4+r][j*16+lr] = acc[j][r];
  __syncthreads();
  for (int idx=t; idx<16*80; idx+=512){
    int rr = idx/80, n = idx%80;
    float s = dsum[0][rr][n];
    #pragma unroll
    for (int q=1;q<8;q++) s += dsum[q][rr][n];
    dsum[0][rr][n] = s;
    if (n < 16) dbcc[rr][n] = s;
  }
  __syncthreads();
  if (t < 256){
    int row = t>>4, ln = t&15;
    float p = dsum[0][row][16+ln]*dsum[0][row][48+ln]
            + dsum[0][row][32+ln]*dsum[0][row][64+ln];
    p += __shfl_xor(p, 8); p += __shfl_xor(p, 4); p += __shfl_xor(p, 2); p += __shfl_xor(p, 1);
    if (ln==0) sS[row] = p;
  }
  __syncthreads();
  int e = 2*t;
  float2 wdtr[16];
  #pragma unroll
  for (int r=0;r<16;r++) wdtr[r] = *(const float2*)(Wdt + (size_t)r*DI + e);
  float2 bd = *(const float2*)(bdt + e);
  float2 dd = *(const float2*)(Dd + e);
  // depth-2 rotating prefetch of xi/sz
  unsigned xp0 = *(const unsigned*)(xi + (size_t)(r0+0)*DI + e);
  unsigned zp0 = *(const unsigned*)(sz + (size_t)(r0+0)*DI + e);
  unsigned xp1 = *(const unsigned*)(xi + (size_t)(r0+1)*DI + e);
  unsigned zp1 = *(const unsigned*)(sz + (size_t)(r0+1)*DI + e);
  #pragma unroll
  for (int row=0; row<16; ++row){
    unsigned cx = xp0, cz = zp0;
    xp0 = xp1; zp0 = zp1;
    if (row < 14){
      xp1 = *(const unsigned*)(xi + (size_t)(r0+row+2)*DI + e);
      zp1 = *(const unsigned*)(sz + (size_t)(r0+row+2)*DI + e);
    }
    float4 d0 = *(const float4*)&dbcc[row][0];
    float4 d1 = *(const float4*)&dbcc[row][4];
    float4 d2 = *(const float4*)&dbcc[row][8];
    float4 d3 = *(const float4*)&dbcc[row][12];
    float u0 = bd.x, u1 = bd.y;
    u0 = fmaf(wdtr[ 0].x, d0.x, u0); u1 = fmaf(wdtr[ 0].y, d0.x, u1);
    u0 = fmaf(wdtr[ 1].x, d0.y, u0); u1 = fmaf(wdtr[ 1].y, d0.y, u1);
    u0 = fmaf(wdtr[ 2].x, d0.z, u0); u1 = fmaf(wdtr[ 2].y, d0.z, u1);
    u0 = fmaf(wdtr[ 3].x, d0.w, u0); u1 = fmaf(wdtr[ 3].y, d0.w, u1);
    u0 = fmaf(wdtr[ 4].x, d1.x, u0); u1 = fmaf(wdtr[ 4].y, d1.x, u1);
    u0 = fmaf(wdtr[ 5].x, d1.y, u0); u1 = fmaf(wdtr[ 5].y, d1.y, u1);
    u0 = fmaf(wdtr[ 6].x, d1.z, u0); u1 = fmaf(wdtr[ 6].y, d1.z, u1);
    u0 = fmaf(wdtr[ 7].x, d1.w, u0); u1 = fmaf(wdtr[ 7].y, d1.w, u1);
    u0 = fmaf(wdtr[ 8].x, d2.x, u0); u1 = fmaf(wdtr[ 8].y, d2.x, u1);
    u0 = fmaf(wdtr[ 9].x, d2.y, u0); u1 = fmaf(wdtr[ 9].y, d2.y, u1);
    u0 = fmaf(wdtr[10].x, d2.z, u0); u1 = fmaf(wdtr[10].y, d2.z, u1);
    u0 = fmaf(wdtr[11].x, d2.w, u0); u1 = fmaf(wdtr[11].y, d2.w, u1);
    u0 = fmaf(wdtr[12].x, d3.x, u0); u1 = fmaf(wdtr[12].y, d3.x, u1);
    u0 = fmaf(wdtr[13].x, d3.y, u0); u1 = fmaf(wdtr[13].y, d3.y, u1);
    u0 = fmaf(wdtr[14].x, d3.z, u0); u1 = fmaf(wdtr[14].y, d3.z, u1);
    u0 = fmaf(wdtr[15].x, d3.w, u0); u1 = fmaf(wdtr[15].y, d3.w, u1);
    float srow = sS[row];
    float dl0 = softplusf(u0), dl1 = softplusf(u1);
    ushort2 xvv = *(ushort2*)&cx;
    ushort2 zvv = *(ushort2*)&cz;
    ushort2 ov;
    ov.x = f2bf(bf2f(xvv.x) * fmaf(dl0, srow, dd.x) * bf2f(zvv.x));
    ov.y = f2bf(bf2f(xvv.y) * fmaf(dl1, srow, dd.y) * bf2f(zvv.y));
    size_t o = (size_t)(r0+row)*DI + e;
    *(ushort2*)(y + o) = ov;
  }
}

// ---------- k_blk1: 32x64 tile, BK=256 one-shot chunks, y @ WoutT^T -> h +=, hb, pssq (+pfin last) ----------
__global__ __launch_bounds__(256) void k_blk1(
    const ushort* __restrict__ A,    // y [4096][1024]
    const ushort* __restrict__ Bt,   // WoutT [256][1024]
    float* __restrict__ h, ushort* __restrict__ hb, float* __restrict__ pssq,
    const float* __restrict__ Wf, float* __restrict__ pfin)
{
  __shared__ __align__(16) ushort As[32][256];  // 16 KB
  __shared__ __align__(16) ushort Bs[64][256];  // 32 KB
  int t = threadIdx.x, wid = t>>6, lane = t&63;
  int wr = wid>>1, wc = wid&1, lr = lane&15, lk = lane>>4;
  int row0 = blockIdx.x*32, col0 = blockIdx.y*64;
  int lrow = lane>>5, lch = lane&31;
  f32x4 acc[2] = {};

  for (int kc=0; kc<4; ++kc){
    int ko = kc*256;
    #pragma unroll
    for (int q=0;q<4;q++){
      int rr = wid*8 + q*2 + lrow;
      async_copy16(&As[wid*8 + q*2][0], A  + (size_t)(row0+rr)*DI + ko + ((lch ^ (rr&7))<<3));
    }
    #pragma unroll
    for (int q=0;q<8;q++){
      int rr = wid*16 + q*2 + lrow;
      async_copy16(&Bs[wid*16 + q*2][0], Bt + (size_t)(col0+rr)*DI + ko + ((lch ^ (rr&7))<<3));
    }
    __syncthreads();
    #pragma unroll
    for (int kk=0;kk<8;kk++){
      int rr = wr*16 + lr;
      bf16x8 a = *(const bf16x8*)&As[rr][(((kk<<2)|lk) ^ (rr&7))<<3];
      #pragma unroll
      for (int j=0;j<2;j++){
        int cc = wc*32 + j*16 + lr;
        bf16x8 b = *(const bf16x8*)&Bs[cc][(((kk<<2)|lk) ^ (cc&7))<<3];
        acc[j] = __builtin_amdgcn_mfma_f32_16x16x32_bf16(a, b, acc[j], 0,0,0);
      }
    }
    __syncthreads();
  }

  float* ls = (float*)&As[0][0];          // [32][68]
  #pragma unroll
  for (int j=0;j<2;j++){
    int cl = wc*32 + j*16 + lr;
    #pragma unroll
    for (int r=0;r<4;r++)
      ls[(wr*16 + lk*4 + r)*68 + cl] = acc[j][r];
  }
  __syncthreads();
  int rl = t>>3, c8 = (t&7)*8;
  size_t o = (size_t)(row0+rl)*DM + col0 + c8;
  float4 hv0, hv1;
  {
    float4 add = *(float4*)&ls[rl*68 + c8];
    hv0 = *(float4*)&h[o];
    hv0.x += add.x; hv0.y += add.y; hv0.z += add.z; hv0.w += add.w;
    *(float4*)&h[o] = hv0;
  }
  {
    float4 add = *(float4*)&ls[rl*68 + c8 + 4];
    hv1 = *(float4*)&h[o + 4];
    hv1.x += add.x; hv1.y += add.y; hv1.z += add.z; hv1.w += add.w;
    *(float4*)&h[o + 4] = hv1;
  }
  // bf16 copy for next layer's A-operand
  uint4 hw;
  hw.x = pack2(hv0.x, hv0.y); hw.y = pack2(hv0.z, hv0.w);
  hw.z = pack2(hv1.x, hv1.y); hw.w = pack2(hv1.z, hv1.w);
  *(uint4*)(hb + o) = hw;
  // per-colblock ssq partial
  float sq = hv0.x*hv0.x + hv0.y*hv0.y + hv0.z*hv0.z + hv0.w*hv0.w
           + hv1.x*hv1.x + hv1.y*hv1.y + hv1.z*hv1.z + hv1.w*hv1.w;
  sq += __shfl_xor(sq, 1); sq += __shfl_xor(sq, 2); sq += __shfl_xor(sq, 4);
  if ((t&7)==0) pssq[(size_t)blockIdx.y*BATCH + row0 + rl] = sq;
  // last layer: per-colblock final-dot partial
  if (Wf){
    const float* wfp = Wf + col0 + c8;
    float pf = hv0.x*wfp[0] + hv0.y*wfp[1] + hv0.z*wfp[2] + hv0.w*wfp[3]
             + hv1.x*wfp[4] + hv1.y*wfp[5] + hv1.z*wfp[6] + hv1.w*wfp[7];
    pf += __shfl_xor(pf, 1); pf += __shfl_xor(pf, 2); pf += __shfl_xor(pf, 4);
    if ((t&7)==0) pfin[(size_t)blockIdx.y*BATCH + row0 + rl] = pf;
  }
}

// ---------- k_final: out = sigmoid(sum pfin + bf) ----------
__global__ __launch_bounds__(256) void k_final(const float* __restrict__ pfin,
    const float* __restrict__ bf, float* __restrict__ out){
  int i = blockIdx.x*256 + threadIdx.x;
  float ft = pfin[i] + pfin[BATCH+i] + pfin[2*BATCH+i] + pfin[3*BATCH+i] + bf[0];
  out[i] = 1.0f/(1.0f + __expf(-ft));
}

extern "C" void kernel_launch(void* const* d_in, const int* in_sizes, int n_in,
                              void* d_out, int out_size, void* d_ws, size_t ws_size,
                              hipStream_t stream){
  const float* x   = (const float*)d_in[0];
  const float* Wp  = (const float*)d_in[1];
  const float* bp  = (const float*)d_in[2];
  const float* nw  = (const float*)d_in[3];
  const float* Win = (const float*)d_in[4];
  const float* cw  = (const float*)d_in[5];
  const float* cb  = (const float*)d_in[6];
  const float* Wx  = (const float*)d_in[7];
  const float* Wdt = (const float*)d_in[8];
  const float* bdt = (const float*)d_in[9];
  const float* Dd  = (const float*)d_in[11];   // A_log (d_in[10]) is dead: scan length 1, h0 = 0
  const float* Wout= (const float*)d_in[12];
  const float* Wf  = (const float*)d_in[13];
  const float* bf  = (const float*)d_in[14];
  float* out = (float*)d_out;

  char* wsb = (char*)d_ws;
  float*  h    = (float*)wsb;  wsb += (size_t)BATCH*DM*4;          // 4 MB
  ushort* hb   = (ushort*)wsb; wsb += (size_t)BATCH*DM*2;          // 2 MB
  ushort* xi   = (ushort*)wsb; wsb += (size_t)BATCH*DI*2;          // 8 MB
  ushort* sz   = (ushort*)wsb; wsb += (size_t)BATCH*DI*2;          // 8 MB
  ushort* WinT = (ushort*)wsb; wsb += (size_t)NL*2*DI*DM*2;        // 4 MB
  ushort* WoutT= (ushort*)wsb; wsb += (size_t)NL*DM*DI*2;          // 2 MB
  ushort* WxT  = (ushort*)wsb; wsb += (size_t)NL*80*DI*2;          // 0.64 MB
  float*  pssq = (float*)wsb;  wsb += (size_t)4*BATCH*4;           // 64 KB
  float*  pfin = (float*)wsb;  wsb += (size_t)4*BATCH*4;           // 64 KB

  k_pre<<<1104, 256, 0, stream>>>(Win, Wout, Wx, nw, WinT, WoutT, WxT,
                                  x, Wp, bp, h, hb, pssq);
  for (int l=0;l<NL;l++){
    k_blk0<<<dim3(BATCH/64, (2*DI)/128), 256, 0, stream>>>(
        hb, pssq, WinT + (size_t)l*2*DI*DM,
        cw + (size_t)l*DI*16, cb + (size_t)l*DI, xi, sz);
    k_ssm<<<BATCH/16, 512, 0, stream>>>(xi, sz, WxT + (size_t)l*80*DI,
        Wdt + (size_t)l*16*DI, bdt + (size_t)l*DI, Dd + (size_t)l*DI, xi);
    k_blk1<<<dim3(BATCH/32, DM/64), 256, 0, stream>>>(
        xi, WoutT + (size_t)l*DM*DI, h, hb, pssq,
        (l == NL-1) ? Wf : nullptr, pfin);
  }
  k_final<<<BATCH/256, 256, 0, stream>>>(pfin, bf, out);
}